// Round 7
// baseline (316.929 us; speedup 1.0000x reference)
//
#include <hip/hip_runtime.h>
#include <hip/hip_bf16.h>

typedef unsigned short ushort_t;
typedef unsigned int uint_t;
typedef unsigned char uchar_t;

typedef __attribute__((ext_vector_type(8))) short bf16x8;
typedef __attribute__((ext_vector_type(4))) float f32x4;
typedef __attribute__((ext_vector_type(2))) float f32x2;

__device__ __forceinline__ float bf2f(ushort_t u) {
    union { uint_t i; float f; } v; v.i = ((uint_t)u) << 16; return v.f;
}
__device__ __forceinline__ ushort_t f2bf(float f) {
    __hip_bfloat16 h = __float2bfloat16(f);
    ushort_t u; __builtin_memcpy(&u, &h, 2); return u;
}
__device__ __forceinline__ float leaky(float v) { return (v > 0.f) ? v : 0.2f * v; }

#define PO_AS1 0
#define PO_AD1 512
#define PO_B1  1024
#define PO_W2  1536
#define PO_AS2 6656
#define PO_AD2 6666
#define PO_B2  6676
#define PTOT   6686

__device__ __forceinline__ bool detect_fp32_local(const ushort_t* __restrict__ xa) {
    __shared__ int cnt;
    if (threadIdx.x == 0) cnt = 0;
    __syncthreads();
    int bad = 0;
    for (int i = threadIdx.x; i < 4096; i += 256) {
        float v = bf2f(xa[i]);
        if (!(fabsf(v) < 1e4f)) bad++;
    }
    if (bad) atomicAdd(&cnt, bad);
    __syncthreads();
    return cnt >= 16;
}

// ---- prep: W1 transpose + params + deg/gacc/gcnt/donecnt zero + va/vb ----
__global__ __launch_bounds__(256) void k_prep(const void* __restrict__ x,
                                              const void* __restrict__ W1,
                                              const void* as1, const void* ad1,
                                              const void* b1, const void* W2,
                                              const void* as2, const void* ad2,
                                              const void* b2,
                                              ushort_t* __restrict__ W1t,
                                              float* __restrict__ prm,
                                              float* __restrict__ vab,
                                              int* __restrict__ deg,
                                              float* __restrict__ gacc,
                                              int* __restrict__ flag, int N) {
    int b = blockIdx.x, t = threadIdx.x;
    if (b < 283) {
        bool isf = detect_fp32_local((const ushort_t*)x);
        if (b == 0 && t == 0) *flag = isf ? 1 : 0;
        if (b < 256) {
            int idx = b * 256 + t;
            int n = idx & 511, k = idx >> 9;
            float v = isf ? ((const float*)W1)[k * 512 + n]
                          : bf2f(((const ushort_t*)W1)[k * 512 + n]);
            W1t[n * 128 + k] = f2bf(v);
        } else {
            int i = (b - 256) * 256 + t;
            if (i < PTOT) {
                const void* src; int off;
                if (i < 512)       { src = as1; off = i; }
                else if (i < 1024) { src = ad1; off = i - 512; }
                else if (i < 1536) { src = b1;  off = i - 1024; }
                else if (i < 6656) { src = W2;  off = i - 1536; }
                else if (i < 6666) { src = as2; off = i - 6656; }
                else if (i < 6676) { src = ad2; off = i - 6666; }
                else               { src = b2;  off = i - 6676; }
                prm[i] = isf ? ((const float*)src)[off] : bf2f(((const ushort_t*)src)[off]);
            }
        }
    } else if (b < 362) {
        int i = (b - 283) * 256 + t;
        if (i < N) deg[i] = 0;
    } else if (b == 362) {
        for (int i = t; i < 768; i += 256) gacc[i] = 0.f;   // 640 sums + 64 counts + donecnt
    } else {
        // va/vb: vab[k][q], q<8 -> x-projection for a_src head q; q>=8 -> a_dst head q-8
        bool isf = detect_fp32_local((const ushort_t*)x);
        int idx = (b - 363) * 256 + t;          // 0..2047
        int k = idx >> 4, q = idx & 15;
        int h = q & 7;
        const void* av = (q < 8) ? as1 : ad1;
        float s = 0.f;
        for (int c = 0; c < 64; ++c) {
            float wv = isf ? ((const float*)W1)[k * 512 + h * 64 + c]
                           : bf2f(((const ushort_t*)W1)[k * 512 + h * 64 + c]);
            float aval = isf ? ((const float*)av)[h * 64 + c]
                             : bf2f(((const ushort_t*)av)[h * 64 + c]);
            s += wv * aval;
        }
        vab[k * 16 + q] = s;
    }
}

// ---- logits (asrc/adst from x·va/vb), x->fp8 quantize, degree histogram ----
__global__ __launch_bounds__(256) void k_logits_hist(const void* __restrict__ xraw,
                                                     const float* __restrict__ vab,
                                                     const int* __restrict__ ei,
                                                     const int* __restrict__ flag,
                                                     uchar_t* __restrict__ xq,
                                                     float* __restrict__ asrcf,
                                                     float* __restrict__ adstf,
                                                     int* __restrict__ deg,
                                                     int E, int Etot) {
    int b = blockIdx.x, t = threadIdx.x;
    if (b >= 1250) {
        int e = (b - 1250) * 256 + t;
        if (e < Etot) {
            int dst = (e < E) ? ei[E + e] : (e - E);
            atomicAdd(&deg[dst], 1);
        }
        return;
    }
    bool isf = (*flag != 0);
    int n = b * 16 + (t >> 4);
    int l = t & 15;
    int ch0 = l * 8;
    float xf[8];
    if (isf) {
        const float4* x4 = (const float4*)xraw + (size_t)n * 32 + l * 2;
        float4 f0 = x4[0], f1 = x4[1];
        xf[0] = f0.x; xf[1] = f0.y; xf[2] = f0.z; xf[3] = f0.w;
        xf[4] = f1.x; xf[5] = f1.y; xf[6] = f1.z; xf[7] = f1.w;
    } else {
        uint4 u = ((const uint4*)((const ushort_t*)xraw + (size_t)n * 128))[l];
        xf[0] = bf2f(u.x & 0xffff); xf[1] = bf2f(u.x >> 16);
        xf[2] = bf2f(u.y & 0xffff); xf[3] = bf2f(u.y >> 16);
        xf[4] = bf2f(u.z & 0xffff); xf[5] = bf2f(u.z >> 16);
        xf[6] = bf2f(u.w & 0xffff); xf[7] = bf2f(u.w >> 16);
    }
    uint_t u0 = (uint_t)__builtin_amdgcn_cvt_pk_fp8_f32(xf[0], xf[1], 0, false);
    u0 = (uint_t)__builtin_amdgcn_cvt_pk_fp8_f32(xf[2], xf[3], (int)u0, true);
    uint_t u1 = (uint_t)__builtin_amdgcn_cvt_pk_fp8_f32(xf[4], xf[5], 0, false);
    u1 = (uint_t)__builtin_amdgcn_cvt_pk_fp8_f32(xf[6], xf[7], (int)u1, true);
    uint2 st; st.x = u0; st.y = u1;
    *((uint2*)(xq + (size_t)n * 128) + l) = st;
    float ps[8], pd[8];
#pragma unroll
    for (int h = 0; h < 8; ++h) { ps[h] = 0.f; pd[h] = 0.f; }
#pragma unroll
    for (int j = 0; j < 8; ++j) {
        const float4* vr = (const float4*)&vab[(ch0 + j) * 16];   // 8KB, L1-resident
        float4 va0 = vr[0], va1 = vr[1], vb0 = vr[2], vb1 = vr[3];
        float xv = xf[j];
        ps[0] += xv * va0.x; ps[1] += xv * va0.y; ps[2] += xv * va0.z; ps[3] += xv * va0.w;
        ps[4] += xv * va1.x; ps[5] += xv * va1.y; ps[6] += xv * va1.z; ps[7] += xv * va1.w;
        pd[0] += xv * vb0.x; pd[1] += xv * vb0.y; pd[2] += xv * vb0.z; pd[3] += xv * vb0.w;
        pd[4] += xv * vb1.x; pd[5] += xv * vb1.y; pd[6] += xv * vb1.z; pd[7] += xv * vb1.w;
    }
#pragma unroll
    for (int off = 1; off <= 8; off <<= 1) {
#pragma unroll
        for (int h = 0; h < 8; ++h) {
            ps[h] += __shfl_xor(ps[h], off, 64);
            pd[h] += __shfl_xor(pd[h], off, 64);
        }
    }
    if (l == 0) {
#pragma unroll
        for (int h = 0; h < 8; ++h) {
            asrcf[n * 8 + h] = ps[h];
            adstf[n * 8 + h] = pd[h];
        }
    }
}

// ---- exclusive scan ----
__global__ __launch_bounds__(256) void k_scan(const int* __restrict__ deg,
                                              int* __restrict__ rowptr,
                                              int* __restrict__ cursor, int N) {
    int b = blockIdx.x, t = threadIdx.x;
    int lane = t & 63, wv = t >> 6;
    __shared__ int ws[4], wt[4];
    __shared__ int sbase;
    int limit = b * 256;
    int p0 = 0, p1 = 0, p2 = 0, p3 = 0;
    int i = t;
    for (; i + 768 < limit; i += 1024) {
        p0 += deg[i]; p1 += deg[i + 256]; p2 += deg[i + 512]; p3 += deg[i + 768];
    }
    for (; i < limit; i += 256) p0 += deg[i];
    int partial = (p0 + p1) + (p2 + p3);
#pragma unroll
    for (int off = 32; off; off >>= 1) partial += __shfl_xor(partial, off, 64);
    if (lane == 0) ws[wv] = partial;
    __syncthreads();
    if (t == 0) sbase = ws[0] + ws[1] + ws[2] + ws[3];
    __syncthreads();
    int base = sbase;
    i = limit + t;
    int v = (i < N) ? deg[i] : 0;
    int inc = v;
#pragma unroll
    for (int off = 1; off < 64; off <<= 1) {
        int u = __shfl_up(inc, off, 64);
        if (lane >= off) inc += u;
    }
    if (lane == 63) wt[wv] = inc;
    __syncthreads();
    int woff = 0;
    for (int w = 0; w < 4; ++w) if (w < wv) woff += wt[w];
    int excl = base + woff + inc - v;
    if (i < N) { rowptr[i + 1] = excl + v; cursor[i] = excl; }
    if (i == 0) rowptr[0] = 0;
}

// ---- scatter + per-edge softmax weights. Nontemporal stores: wcsr/csr_src are
// random 32B/4B partial-line writes -> skip write-allocate RMW fetches. ----
__global__ __launch_bounds__(256) void k_scatter(const int* __restrict__ ei,
                                                 int* __restrict__ cursor,
                                                 const float* __restrict__ asrcf,
                                                 const float* __restrict__ adstf,
                                                 int* __restrict__ csr_src,
                                                 float* __restrict__ wcsr,
                                                 int E, int Etot) {
    int e = blockIdx.x * 256 + threadIdx.x;
    if (e >= Etot) return;
    int src, dst;
    if (e < E) { src = ei[e]; dst = ei[E + e]; } else { src = dst = e - E; }
    int pos = atomicAdd(&cursor[dst], 1);
    __builtin_nontemporal_store(src, &csr_src[pos]);
    const float4* ap = (const float4*)&asrcf[(size_t)src * 8];
    const float4* bp = (const float4*)&adstf[(size_t)dst * 8];
    float4 a0 = ap[0], a1 = ap[1];
    float4 b0 = bp[0], b1 = bp[1];
    f32x4 w0, w1;
    w0.x = __expf(leaky(a0.x + b0.x));
    w0.y = __expf(leaky(a0.y + b0.y));
    w0.z = __expf(leaky(a0.z + b0.z));
    w0.w = __expf(leaky(a0.w + b0.w));
    w1.x = __expf(leaky(a1.x + b1.x));
    w1.y = __expf(leaky(a1.y + b1.y));
    w1.z = __expf(leaky(a1.z + b1.z));
    w1.w = __expf(leaky(a1.w + b1.w));
    f32x4* wp = (f32x4*)&wcsr[(size_t)pos * 8];   // ext_vector type: valid for nontemporal
    __builtin_nontemporal_store(w0, wp);
    __builtin_nontemporal_store(w1, wp + 1);
}

// ---- FUSED aggregation + GEMM + ELU + W2 epilogue, TLP-preserving version:
// 8 nodes/block, ONE FULL WAVE per node in phase A (20000 gather-waves — the
// latency-bound gather keeps R4-aggx parallelism), 16.6KB LDS tile. Phase B:
// M=16 MFMA tile with 8 valid rows (rows 8-15 duplicates, discarded) — 2x
// redundant MFMA is ~free; agg never touches HBM. ----
__global__ __launch_bounds__(512) void k_aggfused(const uchar_t* __restrict__ xq,
                                                  const int* __restrict__ rowptr,
                                                  const int* __restrict__ csr_src,
                                                  const float* __restrict__ wcsr,
                                                  const ushort_t* __restrict__ w1t,
                                                  const float* __restrict__ prm,
                                                  ushort_t* __restrict__ h2,
                                                  float* __restrict__ asrc2f,
                                                  float* __restrict__ adst2f) {
    __shared__ ushort_t sA[8 * 1040];    // 8 node-rows, +16 pad
    int b = blockIdx.x, t = threadIdx.x;
    int m0 = b * 8;
    int wave = t >> 6, lane = t & 63;
    // ---- phase A: wave w aggregates node m0+w (full wave, R4-aggx inner loop) ----
    {
        int n = m0 + wave;
        int start = rowptr[n], end = rowptr[n + 1];
        float acc[16];
        float den[8];
#pragma unroll
        for (int i = 0; i < 16; ++i) acc[i] = 0.f;
#pragma unroll
        for (int h = 0; h < 8; ++h) den[h] = 0.f;
        for (int base = start; base < end; base += 64) {
            int mcap = min(64, end - base);
            int sIdx = csr_src[base + min(lane, mcap - 1)];
            for (int g = 0; g < mcap; g += 4) {
                int s[4]; float4 wA[4], wB[4]; ushort_t xv[4];
#pragma unroll
                for (int j = 0; j < 4; ++j)
                    s[j] = __shfl(sIdx, min(g + j, mcap - 1), 64);
#pragma unroll
                for (int j = 0; j < 4; ++j) {
                    const float4* wp = (const float4*)&wcsr[(size_t)(base + min(g + j, mcap - 1)) * 8];
                    wA[j] = wp[0]; wB[j] = wp[1];
                }
#pragma unroll
                for (int j = 0; j < 4; ++j)
                    xv[j] = *(const ushort_t*)&xq[(size_t)s[j] * 128 + lane * 2];
#pragma unroll
                for (int j = 0; j < 4; ++j) {
                    float msk = (g + j < mcap) ? 1.f : 0.f;
                    f32x2 q = __builtin_amdgcn_cvt_pk_f32_fp8((int)xv[j], false);
                    float w0 = wA[j].x * msk, w1 = wA[j].y * msk, w2 = wA[j].z * msk, w3 = wA[j].w * msk;
                    float w4 = wB[j].x * msk, w5 = wB[j].y * msk, w6 = wB[j].z * msk, w7 = wB[j].w * msk;
                    den[0] += w0; acc[0]  += w0 * q.x; acc[1]  += w0 * q.y;
                    den[1] += w1; acc[2]  += w1 * q.x; acc[3]  += w1 * q.y;
                    den[2] += w2; acc[4]  += w2 * q.x; acc[5]  += w2 * q.y;
                    den[3] += w3; acc[6]  += w3 * q.x; acc[7]  += w3 * q.y;
                    den[4] += w4; acc[8]  += w4 * q.x; acc[9]  += w4 * q.y;
                    den[5] += w5; acc[10] += w5 * q.x; acc[11] += w5 * q.y;
                    den[6] += w6; acc[12] += w6 * q.x; acc[13] += w6 * q.y;
                    den[7] += w7; acc[14] += w7 * q.x; acc[15] += w7 * q.y;
                }
            }
        }
#pragma unroll
        for (int h = 0; h < 8; ++h) {
            float inv = 1.f / (den[h] + 1e-16f);
            uint_t u = (uint_t)f2bf(acc[2 * h] * inv) | ((uint_t)f2bf(acc[2 * h + 1] * inv) << 16);
            *(uint_t*)&sA[wave * 1040 + h * 128 + 2 * lane] = u;
        }
    }
    __syncthreads();
    // ---- phase B: MFMA agg@W1 (waves 0-3; M-tile rows 8-15 are discards) ----
    int mr = lane & 15, quad = lane >> 4;
    f32x4 acc2[8];
#pragma unroll
    for (int ct = 0; ct < 8; ++ct) acc2[ct] = {0.f, 0.f, 0.f, 0.f};
    if (wave < 4) {
        int row = mr & 7;
#pragma unroll
        for (int kk = 0; kk < 4; ++kk) {
            bf16x8 a0 = *reinterpret_cast<const bf16x8*>(
                &sA[row * 1040 + (wave * 2) * 128 + quad * 8 + kk * 32]);
            bf16x8 a1 = *reinterpret_cast<const bf16x8*>(
                &sA[row * 1040 + (wave * 2 + 1) * 128 + quad * 8 + kk * 32]);
            int n0 = wave * 128;
#pragma unroll
            for (int ct = 0; ct < 8; ++ct) {
                bf16x8 bb = *reinterpret_cast<const bf16x8*>(
                    &w1t[(size_t)(n0 + ct * 16 + mr) * 128 + quad * 8 + kk * 32]);
                acc2[ct] = __builtin_amdgcn_mfma_f32_16x16x32_bf16(ct < 4 ? a0 : a1, bb, acc2[ct], 0, 0, 0);
            }
        }
    }
    __syncthreads();                       // all sA reads done before aliasing
    ushort_t* h1s = sA;                    // overlay: 8 x 512 bf16 (8KB <= 16.6KB)
    if (wave < 4 && quad < 2) {
        int col = lane & 15;
        int n0 = wave * 128;
#pragma unroll
        for (int ct = 0; ct < 8; ++ct) {
            int abscol = n0 + ct * 16 + col;
            float bb1 = prm[PO_B1 + abscol];
#pragma unroll
            for (int r = 0; r < 4; ++r) {
                int rowi = quad * 4 + r;           // 0..7 valid node rows
                float v = acc2[ct][r] + bb1;
                v = (v > 0.f) ? v : expm1f(v);     // ELU
                h1s[rowi * 512 + abscol] = f2bf(v);
            }
        }
    }
    __syncthreads();
    // ---- epilogue: wave w -> node m0+w, W2 projection + layer-2 logits ----
    {
        int n = m0 + wave;
        int cb = lane * 8;
        bf16x8 hv = *reinterpret_cast<const bf16x8*>(&h1s[wave * 512 + cb]);
        float p2[10];
#pragma unroll
        for (int c = 0; c < 10; ++c) p2[c] = 0.f;
#pragma unroll
        for (int j = 0; j < 8; ++j) {
            float rv = bf2f((ushort_t)hv[j]);
            const float2* wrow = reinterpret_cast<const float2*>(&prm[PO_W2 + (cb + j) * 10]);
            float2 w01 = wrow[0], w23 = wrow[1], w45 = wrow[2], w67 = wrow[3], w89 = wrow[4];
            p2[0] += rv * w01.x; p2[1] += rv * w01.y;
            p2[2] += rv * w23.x; p2[3] += rv * w23.y;
            p2[4] += rv * w45.x; p2[5] += rv * w45.y;
            p2[6] += rv * w67.x; p2[7] += rv * w67.y;
            p2[8] += rv * w89.x; p2[9] += rv * w89.y;
        }
#pragma unroll
        for (int c = 0; c < 10; ++c)
#pragma unroll
            for (int off = 32; off; off >>= 1)
                p2[c] += __shfl_xor(p2[c], off, 64);
        if (lane == 0) {
            float as = 0.f, ad = 0.f;
#pragma unroll
            for (int c = 0; c < 10; ++c) {
                h2[(size_t)n * 16 + c] = f2bf(p2[c]);   // bf16 32B rows
                as += p2[c] * prm[PO_AS2 + c];
                ad += p2[c] * prm[PO_AD2 + c];
            }
            asrc2f[n] = as; adst2f[n] = ad;
        }
    }
}

// ------- layer-2 softmax+agg, 16 lanes/node, fused mean-pool + counts + final -------
__global__ __launch_bounds__(256) void k_agg2f(const ushort_t* __restrict__ h2,
                                               const float* __restrict__ asrc2f,
                                               const float* __restrict__ adst2f,
                                               const int* __restrict__ rowptr,
                                               const int* __restrict__ csr_src,
                                               const float* __restrict__ prm,
                                               const int* __restrict__ batch,
                                               float* __restrict__ gacc,
                                               float* __restrict__ gcnt,
                                               int* __restrict__ donecnt,
                                               const int* __restrict__ flag,
                                               void* __restrict__ dout) {
    int t = threadIdx.x;
    int grp = t >> 4, l = t & 15;
    int n = blockIdx.x * 16 + grp;
    int start = rowptr[n], end = rowptr[n + 1];
    float adn = adst2f[n];
    float den = 0.f;
    float oc[10];
#pragma unroll
    for (int c = 0; c < 10; ++c) oc[c] = 0.f;
    for (int e = start + l; e < end; e += 16) {
        int s = csr_src[e];
        float lo = asrc2f[s];
        const uint_t* hp = (const uint_t*)(h2 + (size_t)s * 16);
        uint4 ha = *(const uint4*)hp;
        uint_t hb = hp[4];
        float ee = __expf(leaky(lo + adn));
        den += ee;
        oc[0] += ee * bf2f(ha.x & 0xffff); oc[1] += ee * bf2f(ha.x >> 16);
        oc[2] += ee * bf2f(ha.y & 0xffff); oc[3] += ee * bf2f(ha.y >> 16);
        oc[4] += ee * bf2f(ha.z & 0xffff); oc[5] += ee * bf2f(ha.z >> 16);
        oc[6] += ee * bf2f(ha.w & 0xffff); oc[7] += ee * bf2f(ha.w >> 16);
        oc[8] += ee * bf2f(hb & 0xffff);   oc[9] += ee * bf2f(hb >> 16);
    }
#pragma unroll
    for (int off = 8; off; off >>= 1) {
        den += __shfl_xor(den, off, 64);
#pragma unroll
        for (int c = 0; c < 10; ++c) oc[c] += __shfl_xor(oc[c], off, 64);
    }
    __shared__ float sres[16][12];
    __shared__ int sg[16];
    if (l == 0) {
        float invd = 1.f / (den + 1e-16f);
#pragma unroll
        for (int c = 0; c < 10; ++c) sres[grp][c] = oc[c] * invd + prm[PO_B2 + c];
        sres[grp][10] = 1.f;
        sg[grp] = batch[n];
    }
    __syncthreads();
    if (t < 11) {
        int c = t;
        float run = sres[0][c]; int g = sg[0];
        for (int k = 1; k < 16; ++k) {
            if (sg[k] != g) {
                atomicAdd(c < 10 ? &gacc[g * 10 + c] : &gcnt[g], run);
                g = sg[k]; run = 0.f;
            }
            run += sres[k][c];
        }
        atomicAdd(c < 10 ? &gacc[g * 10 + c] : &gcnt[g], run);
    }
    // ---- last block performs the final divide + store ----
    __syncthreads();
    __shared__ int slast;
    if (t == 0) {
        __threadfence();
        int d = atomicAdd(donecnt, 1);
        slast = (d == (int)gridDim.x - 1) ? 1 : 0;
    }
    __syncthreads();
    if (slast && t < 64) {
        __threadfence();
        bool isf = (*flag != 0);
        const volatile float* ga = (const volatile float*)gacc;
        const volatile float* gc = (const volatile float*)gcnt;
        float cnt = fmaxf(gc[t], 1.f);
        for (int c = 0; c < 10; ++c) {
            float r = ga[t * 10 + c] / cnt;
            if (isf) ((float*)dout)[t * 10 + c] = r;
            else     ((ushort_t*)dout)[t * 10 + c] = f2bf(r);
        }
    }
}

extern "C" void kernel_launch(void* const* d_in, const int* in_sizes, int n_in,
                              void* d_out, int out_size, void* d_ws, size_t ws_size,
                              hipStream_t stream) {
    const void* x   = d_in[0];
    const int* ei   = (const int*)d_in[1];
    const int* batch= (const int*)d_in[2];
    const void* W1  = d_in[3];
    const void* as1 = d_in[4];
    const void* ad1 = d_in[5];
    const void* b1  = d_in[6];
    const void* W2  = d_in[7];
    const void* as2 = d_in[8];
    const void* ad2 = d_in[9];
    const void* b2  = d_in[10];

    constexpr int N = 20000, E = 320000, Etot = E + N;
    constexpr int histBlocks = (Etot + 255) / 256;

    char* p = (char*)d_ws;
    auto alloc = [&](size_t bytes) {
        char* r = p; p += (bytes + 255) & ~(size_t)255; return r;
    };
    int* flag       = (int*)alloc(256);
    float* prm      = (float*)alloc((size_t)PTOT * 4);
    float* vab      = (float*)alloc(2048 * 4);
    ushort_t* w1t   = (ushort_t*)alloc(512 * 128 * 2);
    uchar_t* xq     = (uchar_t*)alloc((size_t)N * 128);           // 2.56 MB fp8 x
    float* asrc1f   = (float*)alloc((size_t)N * 8 * 4);
    float* adst1f   = (float*)alloc((size_t)N * 8 * 4);
    float* asrc2f   = (float*)alloc((size_t)N * 4);
    float* adst2f   = (float*)alloc((size_t)N * 4);
    ushort_t* h2    = (ushort_t*)alloc((size_t)N * 16 * 2);       // bf16 32B rows
    float* gacc     = (float*)alloc((size_t)768 * 4);             // sums+counts+done
    int* deg        = (int*)alloc((size_t)N * 4);
    int* rowptr     = (int*)alloc((size_t)(N + 1) * 4);
    int* cursor     = (int*)alloc((size_t)N * 4);
    int* csr_src    = (int*)alloc((size_t)(Etot + 64) * 4);
    float* wcsr     = (float*)alloc(((size_t)Etot * 8 + 1024) * 4);
    float* gcnt     = gacc + 640;
    int* donecnt    = (int*)(gacc + 704);

    k_prep<<<371, 256, 0, stream>>>(x, W1, as1, ad1, b1, W2, as2, ad2, b2,
                                    w1t, prm, vab, deg, gacc, flag, N);
    k_logits_hist<<<1250 + histBlocks, 256, 0, stream>>>(x, vab, ei, flag, xq,
                                                         asrc1f, adst1f, deg, E, Etot);
    k_scan<<<(N + 255) / 256, 256, 0, stream>>>(deg, rowptr, cursor, N);
    k_scatter<<<histBlocks, 256, 0, stream>>>(ei, cursor, asrc1f, adst1f,
                                              csr_src, wcsr, E, Etot);
    k_aggfused<<<N / 8, 512, 0, stream>>>(xq, rowptr, csr_src, wcsr, w1t, prm,
                                          h2, asrc2f, adst2f);
    k_agg2f<<<N / 16, 256, 0, stream>>>(h2, asrc2f, adst2f, rowptr, csr_src, prm,
                                        batch, gacc, gcnt, donecnt, flag, d_out);
}

// Round 8
// 262.899 us; speedup vs baseline: 1.2055x; 1.2055x over previous
//
#include <hip/hip_runtime.h>
#include <hip/hip_bf16.h>

typedef unsigned short ushort_t;
typedef unsigned int uint_t;
typedef unsigned char uchar_t;

typedef __attribute__((ext_vector_type(8))) short bf16x8;
typedef __attribute__((ext_vector_type(4))) float f32x4;
typedef __attribute__((ext_vector_type(2))) float f32x2;

__device__ __forceinline__ float bf2f(ushort_t u) {
    union { uint_t i; float f; } v; v.i = ((uint_t)u) << 16; return v.f;
}
__device__ __forceinline__ ushort_t f2bf(float f) {
    __hip_bfloat16 h = __float2bfloat16(f);
    ushort_t u; __builtin_memcpy(&u, &h, 2); return u;
}
__device__ __forceinline__ uchar_t f2fp8(float v) {
    int p = __builtin_amdgcn_cvt_pk_fp8_f32(v, v, 0, false);
    return (uchar_t)(p & 0xff);
}
__device__ __forceinline__ float leaky(float v) { return (v > 0.f) ? v : 0.2f * v; }

#define PO_AS1 0
#define PO_AD1 512
#define PO_B1  1024
#define PO_W2  1536
#define PO_AS2 6656
#define PO_AD2 6666
#define PO_B2  6676
#define PTOT   6686

__device__ __forceinline__ bool detect_fp32_local(const ushort_t* __restrict__ xa) {
    __shared__ int cnt;
    if (threadIdx.x == 0) cnt = 0;
    __syncthreads();
    int bad = 0;
    for (int i = threadIdx.x; i < 4096; i += 256) {
        float v = bf2f(xa[i]);
        if (!(fabsf(v) < 1e4f)) bad++;
    }
    if (bad) atomicAdd(&cnt, bad);
    __syncthreads();
    return cnt >= 16;
}

// ---- prep: W1 transpose + param normalize + deg zero + gacc/gcnt/donecnt zero ----
__global__ __launch_bounds__(256) void k_prep(const void* __restrict__ x,
                                              const void* __restrict__ W1,
                                              const void* as1, const void* ad1,
                                              const void* b1, const void* W2,
                                              const void* as2, const void* ad2,
                                              const void* b2,
                                              ushort_t* __restrict__ W1t,
                                              float* __restrict__ prm,
                                              int* __restrict__ deg,
                                              float* __restrict__ gacc,
                                              int* __restrict__ flag, int N) {
    int b = blockIdx.x, t = threadIdx.x;
    if (b < 283) {
        bool isf = detect_fp32_local((const ushort_t*)x);
        if (b == 0 && t == 0) *flag = isf ? 1 : 0;
        if (b < 256) {
            int idx = b * 256 + t;
            int n = idx & 511, k = idx >> 9;
            float v = isf ? ((const float*)W1)[k * 512 + n]
                          : bf2f(((const ushort_t*)W1)[k * 512 + n]);
            W1t[n * 128 + k] = f2bf(v);
        } else {
            int i = (b - 256) * 256 + t;
            if (i < PTOT) {
                const void* src; int off;
                if (i < 512)       { src = as1; off = i; }
                else if (i < 1024) { src = ad1; off = i - 512; }
                else if (i < 1536) { src = b1;  off = i - 1024; }
                else if (i < 6656) { src = W2;  off = i - 1536; }
                else if (i < 6666) { src = as2; off = i - 6656; }
                else if (i < 6676) { src = ad2; off = i - 6666; }
                else               { src = b2;  off = i - 6676; }
                prm[i] = isf ? ((const float*)src)[off] : bf2f(((const ushort_t*)src)[off]);
            }
        }
    } else if (b < 362) {
        int i = (b - 283) * 256 + t;
        if (i < N) deg[i] = 0;
    } else {
        for (int i = t; i < 768; i += 256) gacc[i] = 0.f;   // 640 sums + 64 counts + donecnt
    }
}

// ------ fused GEMM1 (+logits) and degree histogram (R1-verified) ------
__global__ __launch_bounds__(256) void k_gemm_hist(const void* __restrict__ xraw,
                                                   const ushort_t* __restrict__ w1t,
                                                   const float* __restrict__ prm,
                                                   const int* __restrict__ ei,
                                                   const int* __restrict__ flag,
                                                   uchar_t* __restrict__ h1,
                                                   float* __restrict__ asrcf,
                                                   float* __restrict__ adstf,
                                                   int* __restrict__ deg,
                                                   int E, int Etot) {
    int b = blockIdx.x, t = threadIdx.x;
    if (b >= 1250) {
        int e = (b - 1250) * 256 + t;
        if (e < Etot) {
            int dst = (e < E) ? ei[E + e] : (e - E);
            atomicAdd(&deg[dst], 1);
        }
        return;
    }
    int wave = t >> 6, lane = t & 63;
    int m0 = b * 16;
    bool isf = (*flag != 0);
    __shared__ ushort_t sA[16 * 128];
    {
        ushort_t tmp[8];
        if (isf) {
            const float4* x4 = (const float4*)((const float*)xraw + (size_t)m0 * 128);
            float4 f0 = x4[2 * t], f1 = x4[2 * t + 1];
            tmp[0] = f2bf(f0.x); tmp[1] = f2bf(f0.y); tmp[2] = f2bf(f0.z); tmp[3] = f2bf(f0.w);
            tmp[4] = f2bf(f1.x); tmp[5] = f2bf(f1.y); tmp[6] = f2bf(f1.z); tmp[7] = f2bf(f1.w);
        } else {
            const uint4* x4 = (const uint4*)((const ushort_t*)xraw + (size_t)m0 * 128);
            uint4 u = x4[t];
            __builtin_memcpy(tmp, &u, 16);
        }
        *reinterpret_cast<uint4*>(&sA[t * 8]) = *reinterpret_cast<uint4*>(tmp);
    }
    __syncthreads();
    int mr = lane & 15, quad = lane >> 4;
    int n0 = wave * 128;
    f32x4 acc[8];
#pragma unroll
    for (int ct = 0; ct < 8; ++ct) acc[ct] = {0.f, 0.f, 0.f, 0.f};
#pragma unroll
    for (int kk = 0; kk < 4; ++kk) {
        bf16x8 a = *reinterpret_cast<const bf16x8*>(&sA[mr * 128 + quad * 8 + kk * 32]);
#pragma unroll
        for (int ct = 0; ct < 8; ++ct) {
            bf16x8 bb = *reinterpret_cast<const bf16x8*>(
                &w1t[(size_t)(n0 + ct * 16 + mr) * 128 + quad * 8 + kk * 32]);
            acc[ct] = __builtin_amdgcn_mfma_f32_16x16x32_bf16(a, bb, acc[ct], 0, 0, 0);
        }
    }
    int col = lane & 15;
#pragma unroll
    for (int hh = 0; hh < 2; ++hh) {
        float ps[4] = {0.f, 0.f, 0.f, 0.f}, pd[4] = {0.f, 0.f, 0.f, 0.f};
#pragma unroll
        for (int c4 = 0; c4 < 4; ++c4) {
            int ct = hh * 4 + c4;
            int abscol = n0 + ct * 16 + col;
            float asv = prm[PO_AS1 + abscol];
            float adv = prm[PO_AD1 + abscol];
#pragma unroll
            for (int r = 0; r < 4; ++r) {
                h1[(size_t)(m0 + quad * 4 + r) * 512 + abscol] = f2fp8(acc[ct][r]);
                ps[r] += acc[ct][r] * asv;
                pd[r] += acc[ct][r] * adv;
            }
        }
#pragma unroll
        for (int off = 1; off <= 8; off <<= 1) {
#pragma unroll
            for (int r = 0; r < 4; ++r) {
                ps[r] += __shfl_xor(ps[r], off, 64);
                pd[r] += __shfl_xor(pd[r], off, 64);
            }
        }
        if (col == 0) {
            int head = 2 * wave + hh;
#pragma unroll
            for (int r = 0; r < 4; ++r) {
                asrcf[(m0 + quad * 4 + r) * 8 + head] = ps[r];
                adstf[(m0 + quad * 4 + r) * 8 + head] = pd[r];
            }
        }
    }
}

// ---- exclusive scan (4-way unrolled prefix re-read) ----
__global__ __launch_bounds__(256) void k_scan(const int* __restrict__ deg,
                                              int* __restrict__ rowptr,
                                              int* __restrict__ cursor, int N) {
    int b = blockIdx.x, t = threadIdx.x;
    int lane = t & 63, wv = t >> 6;
    __shared__ int ws[4], wt[4];
    __shared__ int sbase;
    int limit = b * 256;
    int p0 = 0, p1 = 0, p2 = 0, p3 = 0;
    int i = t;
    for (; i + 768 < limit; i += 1024) {
        p0 += deg[i]; p1 += deg[i + 256]; p2 += deg[i + 512]; p3 += deg[i + 768];
    }
    for (; i < limit; i += 256) p0 += deg[i];
    int partial = (p0 + p1) + (p2 + p3);
#pragma unroll
    for (int off = 32; off; off >>= 1) partial += __shfl_xor(partial, off, 64);
    if (lane == 0) ws[wv] = partial;
    __syncthreads();
    if (t == 0) sbase = ws[0] + ws[1] + ws[2] + ws[3];
    __syncthreads();
    int base = sbase;
    i = limit + t;
    int v = (i < N) ? deg[i] : 0;
    int inc = v;
#pragma unroll
    for (int off = 1; off < 64; off <<= 1) {
        int u = __shfl_up(inc, off, 64);
        if (lane >= off) inc += u;
    }
    if (lane == 63) wt[wv] = inc;
    __syncthreads();
    int woff = 0;
    for (int w = 0; w < 4; ++w) if (w < wv) woff += wt[w];
    int excl = base + woff + inc - v;
    if (i < N) { rowptr[i + 1] = excl + v; cursor[i] = excl; }
    if (i == 0) rowptr[0] = 0;
}

// ---- scatter + per-edge softmax weights; nontemporal stores skip
// write-allocate RMW on the random 4B/32B partial-line writes ----
__global__ __launch_bounds__(256) void k_scatter(const int* __restrict__ ei,
                                                 int* __restrict__ cursor,
                                                 const float* __restrict__ asrcf,
                                                 const float* __restrict__ adstf,
                                                 int* __restrict__ csr_src,
                                                 float* __restrict__ wcsr,
                                                 int E, int Etot) {
    int e = blockIdx.x * 256 + threadIdx.x;
    if (e >= Etot) return;
    int src, dst;
    if (e < E) { src = ei[e]; dst = ei[E + e]; } else { src = dst = e - E; }
    int pos = atomicAdd(&cursor[dst], 1);
    __builtin_nontemporal_store(src, &csr_src[pos]);
    const float4* ap = (const float4*)&asrcf[(size_t)src * 8];
    const float4* bp = (const float4*)&adstf[(size_t)dst * 8];
    float4 a0 = ap[0], a1 = ap[1];
    float4 b0 = bp[0], b1 = bp[1];
    f32x4 w0, w1;
    w0.x = __expf(leaky(a0.x + b0.x));
    w0.y = __expf(leaky(a0.y + b0.y));
    w0.z = __expf(leaky(a0.z + b0.z));
    w0.w = __expf(leaky(a0.w + b0.w));
    w1.x = __expf(leaky(a1.x + b1.x));
    w1.y = __expf(leaky(a1.y + b1.y));
    w1.z = __expf(leaky(a1.z + b1.z));
    w1.w = __expf(leaky(a1.w + b1.w));
    f32x4* wp = (f32x4*)&wcsr[(size_t)pos * 8];
    __builtin_nontemporal_store(w0, wp);
    __builtin_nontemporal_store(w1, wp + 1);
}

// --- layer-1 agg + ELU + layer-2 linear&logits. R1-verified structure:
// two waves/node, 8-edge batches, wcsr streamed. h2 now bf16 32B rows. ---
__global__ __launch_bounds__(256) void k_agg1(const uchar_t* __restrict__ h1,
                                              const int* __restrict__ rowptr,
                                              const int* __restrict__ csr_src,
                                              const float* __restrict__ wcsr,
                                              const float* __restrict__ prm,
                                              ushort_t* __restrict__ h2,
                                              float* __restrict__ asrc2f,
                                              float* __restrict__ adst2f) {
    int wid = threadIdx.x >> 6;
    int ni = wid >> 1;          // node slot in block (0..1)
    int half = wid & 1;         // edge-range half
    int n = blockIdx.x * 2 + ni;
    int lane = threadIdx.x & 63;
    int hh = lane >> 3;
    int cb = lane * 8;
    int start = rowptr[n], end = rowptr[n + 1];
    int deg = end - start;
    int mid = (deg + 1) >> 1;
    int es = start + (half ? mid : 0);
    int ee = half ? end : (start + mid);
    float a0 = 0.f, a1 = 0.f, a2 = 0.f, a3 = 0.f, a4 = 0.f, a5 = 0.f, a6 = 0.f, a7 = 0.f;
    float den = 0.f;
    for (int base = es; base < ee; base += 64) {
        int m = min(64, ee - base);
        int sIdx = csr_src[base + min(lane, m - 1)];
        for (int g = 0; g < m; g += 8) {
            int s[8]; float w[8]; uint2 p[8];
#pragma unroll
            for (int j = 0; j < 8; ++j)
                s[j] = __shfl(sIdx, min(g + j, m - 1), 64);
#pragma unroll
            for (int j = 0; j < 8; ++j) {
                float wv = wcsr[(size_t)(base + g + j) * 8 + hh];
                w[j] = (base + g + j < ee) ? wv : 0.f;
            }
#pragma unroll
            for (int j = 0; j < 8; ++j)
                p[j] = *reinterpret_cast<const uint2*>(&h1[(size_t)s[j] * 512 + cb]);
#pragma unroll
            for (int j = 0; j < 8; ++j) {
                float we = w[j];
                den += we;
                f32x2 q0 = __builtin_amdgcn_cvt_pk_f32_fp8((int)p[j].x, false);
                f32x2 q1 = __builtin_amdgcn_cvt_pk_f32_fp8((int)p[j].x, true);
                f32x2 q2 = __builtin_amdgcn_cvt_pk_f32_fp8((int)p[j].y, false);
                f32x2 q3 = __builtin_amdgcn_cvt_pk_f32_fp8((int)p[j].y, true);
                a0 += we * q0.x; a1 += we * q0.y;
                a2 += we * q1.x; a3 += we * q1.y;
                a4 += we * q2.x; a5 += we * q2.y;
                a6 += we * q3.x; a7 += we * q3.y;
            }
        }
    }
    __shared__ float sred[2][64][9];  // stride 9 (odd) -> bank-conflict-free
    if (half) {
        float* sp = sred[ni][lane];
        sp[0] = a0; sp[1] = a1; sp[2] = a2; sp[3] = a3;
        sp[4] = a4; sp[5] = a5; sp[6] = a6; sp[7] = a7; sp[8] = den;
    }
    __syncthreads();
    if (half) return;
    {
        const float* sp = sred[ni][lane];
        a0 += sp[0]; a1 += sp[1]; a2 += sp[2]; a3 += sp[3];
        a4 += sp[4]; a5 += sp[5]; a6 += sp[6]; a7 += sp[7]; den += sp[8];
    }
    float inv = 1.f / (den + 1e-16f);
    float r[8] = {a0, a1, a2, a3, a4, a5, a6, a7};
    float p2[10];
#pragma unroll
    for (int c = 0; c < 10; ++c) p2[c] = 0.f;
#pragma unroll
    for (int j = 0; j < 8; ++j) {
        float rv = r[j] * inv + prm[PO_B1 + cb + j];
        rv = (rv > 0.f) ? rv : expm1f(rv);    // ELU
        const float2* wrow = reinterpret_cast<const float2*>(&prm[PO_W2 + (cb + j) * 10]);
        float2 w01 = wrow[0], w23 = wrow[1], w45 = wrow[2], w67 = wrow[3], w89 = wrow[4];
        p2[0] += rv * w01.x; p2[1] += rv * w01.y;
        p2[2] += rv * w23.x; p2[3] += rv * w23.y;
        p2[4] += rv * w45.x; p2[5] += rv * w45.y;
        p2[6] += rv * w67.x; p2[7] += rv * w67.y;
        p2[8] += rv * w89.x; p2[9] += rv * w89.y;
    }
#pragma unroll
    for (int c = 0; c < 10; ++c)
#pragma unroll
        for (int off = 32; off; off >>= 1)
            p2[c] += __shfl_xor(p2[c], off, 64);
    if (lane == 0) {
        float as = 0.f, ad = 0.f;
#pragma unroll
        for (int c = 0; c < 10; ++c) {
            h2[(size_t)n * 16 + c] = f2bf(p2[c]);   // bf16 32B rows
            as += p2[c] * prm[PO_AS2 + c];
            ad += p2[c] * prm[PO_AD2 + c];
        }
        asrc2f[n] = as; adst2f[n] = ad;
    }
}

// ------- layer-2 softmax+agg, 16 lanes/node, fused mean-pool + counts + final -------
__global__ __launch_bounds__(256) void k_agg2f(const ushort_t* __restrict__ h2,
                                               const float* __restrict__ asrc2f,
                                               const float* __restrict__ adst2f,
                                               const int* __restrict__ rowptr,
                                               const int* __restrict__ csr_src,
                                               const float* __restrict__ prm,
                                               const int* __restrict__ batch,
                                               float* __restrict__ gacc,
                                               float* __restrict__ gcnt,
                                               int* __restrict__ donecnt,
                                               const int* __restrict__ flag,
                                               void* __restrict__ dout) {
    int t = threadIdx.x;
    int grp = t >> 4, l = t & 15;
    int n = blockIdx.x * 16 + grp;
    int start = rowptr[n], end = rowptr[n + 1];
    float adn = adst2f[n];
    float den = 0.f;
    float oc[10];
#pragma unroll
    for (int c = 0; c < 10; ++c) oc[c] = 0.f;
    for (int e = start + l; e < end; e += 16) {
        int s = csr_src[e];
        float lo = asrc2f[s];
        const uint_t* hp = (const uint_t*)(h2 + (size_t)s * 16);
        uint4 ha = *(const uint4*)hp;
        uint_t hb = hp[4];
        float ee = __expf(leaky(lo + adn));
        den += ee;
        oc[0] += ee * bf2f(ha.x & 0xffff); oc[1] += ee * bf2f(ha.x >> 16);
        oc[2] += ee * bf2f(ha.y & 0xffff); oc[3] += ee * bf2f(ha.y >> 16);
        oc[4] += ee * bf2f(ha.z & 0xffff); oc[5] += ee * bf2f(ha.z >> 16);
        oc[6] += ee * bf2f(ha.w & 0xffff); oc[7] += ee * bf2f(ha.w >> 16);
        oc[8] += ee * bf2f(hb & 0xffff);   oc[9] += ee * bf2f(hb >> 16);
    }
#pragma unroll
    for (int off = 8; off; off >>= 1) {
        den += __shfl_xor(den, off, 64);
#pragma unroll
        for (int c = 0; c < 10; ++c) oc[c] += __shfl_xor(oc[c], off, 64);
    }
    __shared__ float sres[16][12];
    __shared__ int sg[16];
    if (l == 0) {
        float invd = 1.f / (den + 1e-16f);
#pragma unroll
        for (int c = 0; c < 10; ++c) sres[grp][c] = oc[c] * invd + prm[PO_B2 + c];
        sres[grp][10] = 1.f;
        sg[grp] = batch[n];
    }
    __syncthreads();
    if (t < 11) {
        int c = t;
        float run = sres[0][c]; int g = sg[0];
        for (int k = 1; k < 16; ++k) {
            if (sg[k] != g) {
                atomicAdd(c < 10 ? &gacc[g * 10 + c] : &gcnt[g], run);
                g = sg[k]; run = 0.f;
            }
            run += sres[k][c];
        }
        atomicAdd(c < 10 ? &gacc[g * 10 + c] : &gcnt[g], run);
    }
    // ---- last block performs the final divide + store ----
    __syncthreads();
    __shared__ int slast;
    if (t == 0) {
        __threadfence();
        int d = atomicAdd(donecnt, 1);
        slast = (d == (int)gridDim.x - 1) ? 1 : 0;
    }
    __syncthreads();
    if (slast && t < 64) {
        __threadfence();
        bool isf = (*flag != 0);
        const volatile float* ga = (const volatile float*)gacc;
        const volatile float* gc = (const volatile float*)gcnt;
        float cnt = fmaxf(gc[t], 1.f);
        for (int c = 0; c < 10; ++c) {
            float r = ga[t * 10 + c] / cnt;
            if (isf) ((float*)dout)[t * 10 + c] = r;
            else     ((ushort_t*)dout)[t * 10 + c] = f2bf(r);
        }
    }
}

extern "C" void kernel_launch(void* const* d_in, const int* in_sizes, int n_in,
                              void* d_out, int out_size, void* d_ws, size_t ws_size,
                              hipStream_t stream) {
    const void* x   = d_in[0];
    const int* ei   = (const int*)d_in[1];
    const int* batch= (const int*)d_in[2];
    const void* W1  = d_in[3];
    const void* as1 = d_in[4];
    const void* ad1 = d_in[5];
    const void* b1  = d_in[6];
    const void* W2  = d_in[7];
    const void* as2 = d_in[8];
    const void* ad2 = d_in[9];
    const void* b2  = d_in[10];

    constexpr int N = 20000, E = 320000, Etot = E + N;
    constexpr int histBlocks = (Etot + 255) / 256;

    char* p = (char*)d_ws;
    auto alloc = [&](size_t bytes) {
        char* r = p; p += (bytes + 255) & ~(size_t)255; return r;
    };
    int* flag       = (int*)alloc(256);
    float* prm      = (float*)alloc((size_t)PTOT * 4);
    ushort_t* w1t   = (ushort_t*)alloc(512 * 128 * 2);
    uchar_t* h1     = (uchar_t*)alloc((size_t)N * 512);           // 10.24 MB fp8
    float* asrc1f   = (float*)alloc((size_t)N * 8 * 4);
    float* adst1f   = (float*)alloc((size_t)N * 8 * 4);
    float* asrc2f   = (float*)alloc((size_t)N * 4);
    float* adst2f   = (float*)alloc((size_t)N * 4);
    ushort_t* h2    = (ushort_t*)alloc((size_t)N * 16 * 2);       // bf16 32B rows
    float* gacc     = (float*)alloc((size_t)768 * 4);             // sums+counts+done
    int* deg        = (int*)alloc((size_t)N * 4);
    int* rowptr     = (int*)alloc((size_t)(N + 1) * 4);
    int* cursor     = (int*)alloc((size_t)N * 4);
    int* csr_src    = (int*)alloc((size_t)(Etot + 64) * 4);
    float* wcsr     = (float*)alloc(((size_t)Etot * 8 + 128) * 4);
    float* gcnt     = gacc + 640;
    int* donecnt    = (int*)(gacc + 704);

    k_prep<<<363, 256, 0, stream>>>(x, W1, as1, ad1, b1, W2, as2, ad2, b2,
                                    w1t, prm, deg, gacc, flag, N);
    k_gemm_hist<<<1250 + histBlocks, 256, 0, stream>>>(x, w1t, prm, ei, flag, h1,
                                                       asrc1f, adst1f, deg, E, Etot);
    k_scan<<<(N + 255) / 256, 256, 0, stream>>>(deg, rowptr, cursor, N);
    k_scatter<<<histBlocks, 256, 0, stream>>>(ei, cursor, asrc1f, adst1f,
                                              csr_src, wcsr, E, Etot);
    k_agg1<<<N / 2, 256, 0, stream>>>(h1, rowptr, csr_src, wcsr, prm,
                                      h2, asrc2f, adst2f);
    k_agg2f<<<N / 16, 256, 0, stream>>>(h2, asrc2f, adst2f, rowptr, csr_src, prm,
                                        batch, gacc, gcnt, donecnt, flag, d_out);
}

// Round 9
// 239.635 us; speedup vs baseline: 1.3225x; 1.0971x over previous
//
#include <hip/hip_runtime.h>
#include <hip/hip_bf16.h>

typedef unsigned short ushort_t;
typedef unsigned int uint_t;
typedef unsigned char uchar_t;

typedef __attribute__((ext_vector_type(8))) short bf16x8;
typedef __attribute__((ext_vector_type(4))) float f32x4;
typedef __attribute__((ext_vector_type(2))) float f32x2;

__device__ __forceinline__ float bf2f(ushort_t u) {
    union { uint_t i; float f; } v; v.i = ((uint_t)u) << 16; return v.f;
}
__device__ __forceinline__ ushort_t f2bf(float f) {
    __hip_bfloat16 h = __float2bfloat16(f);
    ushort_t u; __builtin_memcpy(&u, &h, 2); return u;
}
__device__ __forceinline__ uchar_t f2fp8(float v) {
    int p = __builtin_amdgcn_cvt_pk_fp8_f32(v, v, 0, false);
    return (uchar_t)(p & 0xff);
}
__device__ __forceinline__ float leaky(float v) { return (v > 0.f) ? v : 0.2f * v; }

#define PO_AS1 0
#define PO_AD1 512
#define PO_B1  1024
#define PO_W2  1536
#define PO_AS2 6656
#define PO_AD2 6666
#define PO_B2  6676
#define PTOT   6686

__device__ __forceinline__ bool detect_fp32_local(const ushort_t* __restrict__ xa) {
    __shared__ int cnt;
    if (threadIdx.x == 0) cnt = 0;
    __syncthreads();
    int bad = 0;
    for (int i = threadIdx.x; i < 4096; i += 256) {
        float v = bf2f(xa[i]);
        if (!(fabsf(v) < 1e4f)) bad++;
    }
    if (bad) atomicAdd(&cnt, bad);
    __syncthreads();
    return cnt >= 16;
}

// ---- prep: W1 transpose + param normalize + deg zero + gacc/gcnt/donecnt zero ----
__global__ __launch_bounds__(256) void k_prep(const void* __restrict__ x,
                                              const void* __restrict__ W1,
                                              const void* as1, const void* ad1,
                                              const void* b1, const void* W2,
                                              const void* as2, const void* ad2,
                                              const void* b2,
                                              ushort_t* __restrict__ W1t,
                                              float* __restrict__ prm,
                                              int* __restrict__ deg,
                                              float* __restrict__ gacc,
                                              int* __restrict__ flag, int N) {
    int b = blockIdx.x, t = threadIdx.x;
    if (b < 283) {
        bool isf = detect_fp32_local((const ushort_t*)x);
        if (b == 0 && t == 0) *flag = isf ? 1 : 0;
        if (b < 256) {
            int idx = b * 256 + t;
            int n = idx & 511, k = idx >> 9;
            float v = isf ? ((const float*)W1)[k * 512 + n]
                          : bf2f(((const ushort_t*)W1)[k * 512 + n]);
            W1t[n * 128 + k] = f2bf(v);
        } else {
            int i = (b - 256) * 256 + t;
            if (i < PTOT) {
                const void* src; int off;
                if (i < 512)       { src = as1; off = i; }
                else if (i < 1024) { src = ad1; off = i - 512; }
                else if (i < 1536) { src = b1;  off = i - 1024; }
                else if (i < 6656) { src = W2;  off = i - 1536; }
                else if (i < 6666) { src = as2; off = i - 6656; }
                else if (i < 6676) { src = ad2; off = i - 6666; }
                else               { src = b2;  off = i - 6676; }
                prm[i] = isf ? ((const float*)src)[off] : bf2f(((const ushort_t*)src)[off]);
            }
        }
    } else if (b < 362) {
        int i = (b - 283) * 256 + t;
        if (i < N) deg[i] = 0;
    } else {
        for (int i = t; i < 768; i += 256) gacc[i] = 0.f;   // 640 sums + 64 counts + donecnt
    }
}

// ------ fused GEMM1 (+logits) and degree histogram (R1-verified) ------
__global__ __launch_bounds__(256) void k_gemm_hist(const void* __restrict__ xraw,
                                                   const ushort_t* __restrict__ w1t,
                                                   const float* __restrict__ prm,
                                                   const int* __restrict__ ei,
                                                   const int* __restrict__ flag,
                                                   uchar_t* __restrict__ h1,
                                                   float* __restrict__ asrcf,
                                                   float* __restrict__ adstf,
                                                   int* __restrict__ deg,
                                                   int E, int Etot) {
    int b = blockIdx.x, t = threadIdx.x;
    if (b >= 1250) {
        int e = (b - 1250) * 256 + t;
        if (e < Etot) {
            int dst = (e < E) ? ei[E + e] : (e - E);
            atomicAdd(&deg[dst], 1);
        }
        return;
    }
    int wave = t >> 6, lane = t & 63;
    int m0 = b * 16;
    bool isf = (*flag != 0);
    __shared__ ushort_t sA[16 * 128];
    {
        ushort_t tmp[8];
        if (isf) {
            const float4* x4 = (const float4*)((const float*)xraw + (size_t)m0 * 128);
            float4 f0 = x4[2 * t], f1 = x4[2 * t + 1];
            tmp[0] = f2bf(f0.x); tmp[1] = f2bf(f0.y); tmp[2] = f2bf(f0.z); tmp[3] = f2bf(f0.w);
            tmp[4] = f2bf(f1.x); tmp[5] = f2bf(f1.y); tmp[6] = f2bf(f1.z); tmp[7] = f2bf(f1.w);
        } else {
            const uint4* x4 = (const uint4*)((const ushort_t*)xraw + (size_t)m0 * 128);
            uint4 u = x4[t];
            __builtin_memcpy(tmp, &u, 16);
        }
        *reinterpret_cast<uint4*>(&sA[t * 8]) = *reinterpret_cast<uint4*>(tmp);
    }
    __syncthreads();
    int mr = lane & 15, quad = lane >> 4;
    int n0 = wave * 128;
    f32x4 acc[8];
#pragma unroll
    for (int ct = 0; ct < 8; ++ct) acc[ct] = {0.f, 0.f, 0.f, 0.f};
#pragma unroll
    for (int kk = 0; kk < 4; ++kk) {
        bf16x8 a = *reinterpret_cast<const bf16x8*>(&sA[mr * 128 + quad * 8 + kk * 32]);
#pragma unroll
        for (int ct = 0; ct < 8; ++ct) {
            bf16x8 bb = *reinterpret_cast<const bf16x8*>(
                &w1t[(size_t)(n0 + ct * 16 + mr) * 128 + quad * 8 + kk * 32]);
            acc[ct] = __builtin_amdgcn_mfma_f32_16x16x32_bf16(a, bb, acc[ct], 0, 0, 0);
        }
    }
    int col = lane & 15;
#pragma unroll
    for (int hh = 0; hh < 2; ++hh) {
        float ps[4] = {0.f, 0.f, 0.f, 0.f}, pd[4] = {0.f, 0.f, 0.f, 0.f};
#pragma unroll
        for (int c4 = 0; c4 < 4; ++c4) {
            int ct = hh * 4 + c4;
            int abscol = n0 + ct * 16 + col;
            float asv = prm[PO_AS1 + abscol];
            float adv = prm[PO_AD1 + abscol];
#pragma unroll
            for (int r = 0; r < 4; ++r) {
                h1[(size_t)(m0 + quad * 4 + r) * 512 + abscol] = f2fp8(acc[ct][r]);
                ps[r] += acc[ct][r] * asv;
                pd[r] += acc[ct][r] * adv;
            }
        }
#pragma unroll
        for (int off = 1; off <= 8; off <<= 1) {
#pragma unroll
            for (int r = 0; r < 4; ++r) {
                ps[r] += __shfl_xor(ps[r], off, 64);
                pd[r] += __shfl_xor(pd[r], off, 64);
            }
        }
        if (col == 0) {
            int head = 2 * wave + hh;
#pragma unroll
            for (int r = 0; r < 4; ++r) {
                asrcf[(m0 + quad * 4 + r) * 8 + head] = ps[r];
                adstf[(m0 + quad * 4 + r) * 8 + head] = pd[r];
            }
        }
    }
}

// ---- exclusive scan (4-way unrolled prefix re-read) ----
__global__ __launch_bounds__(256) void k_scan(const int* __restrict__ deg,
                                              int* __restrict__ rowptr,
                                              int* __restrict__ cursor, int N) {
    int b = blockIdx.x, t = threadIdx.x;
    int lane = t & 63, wv = t >> 6;
    __shared__ int ws[4], wt[4];
    __shared__ int sbase;
    int limit = b * 256;
    int p0 = 0, p1 = 0, p2 = 0, p3 = 0;
    int i = t;
    for (; i + 768 < limit; i += 1024) {
        p0 += deg[i]; p1 += deg[i + 256]; p2 += deg[i + 512]; p3 += deg[i + 768];
    }
    for (; i < limit; i += 256) p0 += deg[i];
    int partial = (p0 + p1) + (p2 + p3);
#pragma unroll
    for (int off = 32; off; off >>= 1) partial += __shfl_xor(partial, off, 64);
    if (lane == 0) ws[wv] = partial;
    __syncthreads();
    if (t == 0) sbase = ws[0] + ws[1] + ws[2] + ws[3];
    __syncthreads();
    int base = sbase;
    i = limit + t;
    int v = (i < N) ? deg[i] : 0;
    int inc = v;
#pragma unroll
    for (int off = 1; off < 64; off <<= 1) {
        int u = __shfl_up(inc, off, 64);
        if (lane >= off) inc += u;
    }
    if (lane == 63) wt[wv] = inc;
    __syncthreads();
    int woff = 0;
    for (int w = 0; w < 4; ++w) if (w < wv) woff += wt[w];
    int excl = base + woff + inc - v;
    if (i < N) { rowptr[i + 1] = excl + v; cursor[i] = excl; }
    if (i == 0) rowptr[0] = 0;
}

// ---- minimal scatter: csr_src only (weights recomputed in-loop in agg1 —
// R0-proven neutral there; deleting wcsr removes its 11MB write + 11MB read
// and two 32B gathers + 8 exp per edge from this kernel) ----
__global__ __launch_bounds__(256) void k_scatter(const int* __restrict__ ei,
                                                 int* __restrict__ cursor,
                                                 int* __restrict__ csr_src,
                                                 int E, int Etot) {
    int e = blockIdx.x * 256 + threadIdx.x;
    if (e >= Etot) return;
    int src, dst;
    if (e < E) { src = ei[e]; dst = ei[E + e]; } else { src = dst = e - E; }
    int pos = atomicAdd(&cursor[dst], 1);
    csr_src[pos] = src;
}

// --- layer-1 agg + ELU + layer-2 linear&logits. R0-verified structure:
// ONE wave per node (4/block), 8-edge batches, in-loop asrcf gather +
// leaky + exp. h2 bf16 32B rows + as2/ad2 epilogue. ---
__global__ __launch_bounds__(256) void k_agg1(const uchar_t* __restrict__ h1,
                                              const float* __restrict__ asrcf,
                                              const float* __restrict__ adstf,
                                              const int* __restrict__ rowptr,
                                              const int* __restrict__ csr_src,
                                              const float* __restrict__ prm,
                                              ushort_t* __restrict__ h2,
                                              float* __restrict__ asrc2f,
                                              float* __restrict__ adst2f) {
    int n = blockIdx.x * 4 + (threadIdx.x >> 6);
    int lane = threadIdx.x & 63;
    int hh = lane >> 3;
    int cb = lane * 8;
    int start = rowptr[n], end = rowptr[n + 1];
    int deg = end - start;
    float adh = adstf[n * 8 + hh];
    float a0 = 0.f, a1 = 0.f, a2 = 0.f, a3 = 0.f, a4 = 0.f, a5 = 0.f, a6 = 0.f, a7 = 0.f;
    float den = 0.f;
    for (int base = 0; base < deg; base += 64) {
        int m = min(64, deg - base);
        int sIdx = csr_src[start + base + min(lane, m - 1)];
        for (int g = 0; g < m; g += 8) {
            int s[8]; float lo[8]; uint2 p[8];
#pragma unroll
            for (int j = 0; j < 8; ++j)
                s[j] = __shfl(sIdx, min(g + j, m - 1), 64);
#pragma unroll
            for (int j = 0; j < 8; ++j)
                lo[j] = asrcf[s[j] * 8 + hh];
#pragma unroll
            for (int j = 0; j < 8; ++j)
                p[j] = *reinterpret_cast<const uint2*>(&h1[(size_t)s[j] * 512 + cb]);
#pragma unroll
            for (int j = 0; j < 8; ++j) {
                float we = (g + j < m) ? __expf(leaky(lo[j] + adh)) : 0.f;
                den += we;
                f32x2 q0 = __builtin_amdgcn_cvt_pk_f32_fp8((int)p[j].x, false);
                f32x2 q1 = __builtin_amdgcn_cvt_pk_f32_fp8((int)p[j].x, true);
                f32x2 q2 = __builtin_amdgcn_cvt_pk_f32_fp8((int)p[j].y, false);
                f32x2 q3 = __builtin_amdgcn_cvt_pk_f32_fp8((int)p[j].y, true);
                a0 += we * q0.x; a1 += we * q0.y;
                a2 += we * q1.x; a3 += we * q1.y;
                a4 += we * q2.x; a5 += we * q2.y;
                a6 += we * q3.x; a7 += we * q3.y;
            }
        }
    }
    float inv = 1.f / (den + 1e-16f);
    float r[8] = {a0, a1, a2, a3, a4, a5, a6, a7};
    float p2[10];
#pragma unroll
    for (int c = 0; c < 10; ++c) p2[c] = 0.f;
#pragma unroll
    for (int j = 0; j < 8; ++j) {
        float rv = r[j] * inv + prm[PO_B1 + cb + j];
        rv = (rv > 0.f) ? rv : expm1f(rv);    // ELU
        const float2* wrow = reinterpret_cast<const float2*>(&prm[PO_W2 + (cb + j) * 10]);
        float2 w01 = wrow[0], w23 = wrow[1], w45 = wrow[2], w67 = wrow[3], w89 = wrow[4];
        p2[0] += rv * w01.x; p2[1] += rv * w01.y;
        p2[2] += rv * w23.x; p2[3] += rv * w23.y;
        p2[4] += rv * w45.x; p2[5] += rv * w45.y;
        p2[6] += rv * w67.x; p2[7] += rv * w67.y;
        p2[8] += rv * w89.x; p2[9] += rv * w89.y;
    }
#pragma unroll
    for (int c = 0; c < 10; ++c)
#pragma unroll
        for (int off = 32; off; off >>= 1)
            p2[c] += __shfl_xor(p2[c], off, 64);
    if (lane == 0) {
        float as = 0.f, ad = 0.f;
#pragma unroll
        for (int c = 0; c < 10; ++c) {
            h2[(size_t)n * 16 + c] = f2bf(p2[c]);   // bf16 32B rows
            as += p2[c] * prm[PO_AS2 + c];
            ad += p2[c] * prm[PO_AD2 + c];
        }
        asrc2f[n] = as; adst2f[n] = ad;
    }
}

// ------- layer-2 softmax+agg, 16 lanes/node, fused mean-pool + counts + final -------
__global__ __launch_bounds__(256) void k_agg2f(const ushort_t* __restrict__ h2,
                                               const float* __restrict__ asrc2f,
                                               const float* __restrict__ adst2f,
                                               const int* __restrict__ rowptr,
                                               const int* __restrict__ csr_src,
                                               const float* __restrict__ prm,
                                               const int* __restrict__ batch,
                                               float* __restrict__ gacc,
                                               float* __restrict__ gcnt,
                                               int* __restrict__ donecnt,
                                               const int* __restrict__ flag,
                                               void* __restrict__ dout) {
    int t = threadIdx.x;
    int grp = t >> 4, l = t & 15;
    int n = blockIdx.x * 16 + grp;
    int start = rowptr[n], end = rowptr[n + 1];
    float adn = adst2f[n];
    float den = 0.f;
    float oc[10];
#pragma unroll
    for (int c = 0; c < 10; ++c) oc[c] = 0.f;
    for (int e = start + l; e < end; e += 16) {
        int s = csr_src[e];
        float lo = asrc2f[s];
        const uint_t* hp = (const uint_t*)(h2 + (size_t)s * 16);
        uint4 ha = *(const uint4*)hp;
        uint_t hb = hp[4];
        float ee = __expf(leaky(lo + adn));
        den += ee;
        oc[0] += ee * bf2f(ha.x & 0xffff); oc[1] += ee * bf2f(ha.x >> 16);
        oc[2] += ee * bf2f(ha.y & 0xffff); oc[3] += ee * bf2f(ha.y >> 16);
        oc[4] += ee * bf2f(ha.z & 0xffff); oc[5] += ee * bf2f(ha.z >> 16);
        oc[6] += ee * bf2f(ha.w & 0xffff); oc[7] += ee * bf2f(ha.w >> 16);
        oc[8] += ee * bf2f(hb & 0xffff);   oc[9] += ee * bf2f(hb >> 16);
    }
#pragma unroll
    for (int off = 8; off; off >>= 1) {
        den += __shfl_xor(den, off, 64);
#pragma unroll
        for (int c = 0; c < 10; ++c) oc[c] += __shfl_xor(oc[c], off, 64);
    }
    __shared__ float sres[16][12];
    __shared__ int sg[16];
    if (l == 0) {
        float invd = 1.f / (den + 1e-16f);
#pragma unroll
        for (int c = 0; c < 10; ++c) sres[grp][c] = oc[c] * invd + prm[PO_B2 + c];
        sres[grp][10] = 1.f;
        sg[grp] = batch[n];
    }
    __syncthreads();
    if (t < 11) {
        int c = t;
        float run = sres[0][c]; int g = sg[0];
        for (int k = 1; k < 16; ++k) {
            if (sg[k] != g) {
                atomicAdd(c < 10 ? &gacc[g * 10 + c] : &gcnt[g], run);
                g = sg[k]; run = 0.f;
            }
            run += sres[k][c];
        }
        atomicAdd(c < 10 ? &gacc[g * 10 + c] : &gcnt[g], run);
    }
    // ---- last block performs the final divide + store ----
    __syncthreads();
    __shared__ int slast;
    if (t == 0) {
        __threadfence();
        int d = atomicAdd(donecnt, 1);
        slast = (d == (int)gridDim.x - 1) ? 1 : 0;
    }
    __syncthreads();
    if (slast && t < 64) {
        __threadfence();
        bool isf = (*flag != 0);
        const volatile float* ga = (const volatile float*)gacc;
        const volatile float* gc = (const volatile float*)gcnt;
        float cnt = fmaxf(gc[t], 1.f);
        for (int c = 0; c < 10; ++c) {
            float r = ga[t * 10 + c] / cnt;
            if (isf) ((float*)dout)[t * 10 + c] = r;
            else     ((ushort_t*)dout)[t * 10 + c] = f2bf(r);
        }
    }
}

extern "C" void kernel_launch(void* const* d_in, const int* in_sizes, int n_in,
                              void* d_out, int out_size, void* d_ws, size_t ws_size,
                              hipStream_t stream) {
    const void* x   = d_in[0];
    const int* ei   = (const int*)d_in[1];
    const int* batch= (const int*)d_in[2];
    const void* W1  = d_in[3];
    const void* as1 = d_in[4];
    const void* ad1 = d_in[5];
    const void* b1  = d_in[6];
    const void* W2  = d_in[7];
    const void* as2 = d_in[8];
    const void* ad2 = d_in[9];
    const void* b2  = d_in[10];

    constexpr int N = 20000, E = 320000, Etot = E + N;
    constexpr int histBlocks = (Etot + 255) / 256;

    char* p = (char*)d_ws;
    auto alloc = [&](size_t bytes) {
        char* r = p; p += (bytes + 255) & ~(size_t)255; return r;
    };
    int* flag       = (int*)alloc(256);
    float* prm      = (float*)alloc((size_t)PTOT * 4);
    ushort_t* w1t   = (ushort_t*)alloc(512 * 128 * 2);
    uchar_t* h1     = (uchar_t*)alloc((size_t)N * 512);           // 10.24 MB fp8
    float* asrc1f   = (float*)alloc((size_t)N * 8 * 4);
    float* adst1f   = (float*)alloc((size_t)N * 8 * 4);
    float* asrc2f   = (float*)alloc((size_t)N * 4);
    float* adst2f   = (float*)alloc((size_t)N * 4);
    ushort_t* h2    = (ushort_t*)alloc((size_t)N * 16 * 2);       // bf16 32B rows
    float* gacc     = (float*)alloc((size_t)768 * 4);             // sums+counts+done
    int* deg        = (int*)alloc((size_t)N * 4);
    int* rowptr     = (int*)alloc((size_t)(N + 1) * 4);
    int* cursor     = (int*)alloc((size_t)N * 4);
    int* csr_src    = (int*)alloc((size_t)(Etot + 64) * 4);
    float* gcnt     = gacc + 640;
    int* donecnt    = (int*)(gacc + 704);

    k_prep<<<363, 256, 0, stream>>>(x, W1, as1, ad1, b1, W2, as2, ad2, b2,
                                    w1t, prm, deg, gacc, flag, N);
    k_gemm_hist<<<1250 + histBlocks, 256, 0, stream>>>(x, w1t, prm, ei, flag, h1,
                                                       asrc1f, adst1f, deg, E, Etot);
    k_scan<<<(N + 255) / 256, 256, 0, stream>>>(deg, rowptr, cursor, N);
    k_scatter<<<histBlocks, 256, 0, stream>>>(ei, cursor, csr_src, E, Etot);
    k_agg1<<<N / 4, 256, 0, stream>>>(h1, asrc1f, adst1f, rowptr, csr_src, prm,
                                      h2, asrc2f, adst2f);
    k_agg2f<<<N / 16, 256, 0, stream>>>(h2, asrc2f, adst2f, rowptr, csr_src, prm,
                                        batch, gacc, gcnt, donecnt, flag, d_out);
}

// Round 10
// 231.086 us; speedup vs baseline: 1.3715x; 1.0370x over previous
//
#include <hip/hip_runtime.h>
#include <hip/hip_bf16.h>

typedef unsigned short ushort_t;
typedef unsigned int uint_t;
typedef unsigned char uchar_t;

typedef __attribute__((ext_vector_type(8))) short bf16x8;
typedef __attribute__((ext_vector_type(4))) float f32x4;
typedef __attribute__((ext_vector_type(2))) float f32x2;

__device__ __forceinline__ float bf2f(ushort_t u) {
    union { uint_t i; float f; } v; v.i = ((uint_t)u) << 16; return v.f;
}
__device__ __forceinline__ ushort_t f2bf(float f) {
    __hip_bfloat16 h = __float2bfloat16(f);
    ushort_t u; __builtin_memcpy(&u, &h, 2); return u;
}
__device__ __forceinline__ uchar_t f2fp8(float v) {
    int p = __builtin_amdgcn_cvt_pk_fp8_f32(v, v, 0, false);
    return (uchar_t)(p & 0xff);
}
__device__ __forceinline__ float leaky(float v) { return (v > 0.f) ? v : 0.2f * v; }

#define PO_AS1 0
#define PO_AD1 512
#define PO_B1  1024
#define PO_W2  1536
#define PO_AS2 6656
#define PO_AD2 6666
#define PO_B2  6676
#define PTOT   6686

__device__ __forceinline__ bool detect_fp32_local(const ushort_t* __restrict__ xa) {
    __shared__ int cnt;
    if (threadIdx.x == 0) cnt = 0;
    __syncthreads();
    int bad = 0;
    for (int i = threadIdx.x; i < 4096; i += 256) {
        float v = bf2f(xa[i]);
        if (!(fabsf(v) < 1e4f)) bad++;
    }
    if (bad) atomicAdd(&cnt, bad);
    __syncthreads();
    return cnt >= 16;
}

// ---- prep: W1 transpose + param normalize + deg zero + gacc/gcnt/donecnt zero ----
__global__ __launch_bounds__(256) void k_prep(const void* __restrict__ x,
                                              const void* __restrict__ W1,
                                              const void* as1, const void* ad1,
                                              const void* b1, const void* W2,
                                              const void* as2, const void* ad2,
                                              const void* b2,
                                              ushort_t* __restrict__ W1t,
                                              float* __restrict__ prm,
                                              int* __restrict__ deg,
                                              float* __restrict__ gacc,
                                              int* __restrict__ flag, int N) {
    int b = blockIdx.x, t = threadIdx.x;
    if (b < 283) {
        bool isf = detect_fp32_local((const ushort_t*)x);
        if (b == 0 && t == 0) *flag = isf ? 1 : 0;
        if (b < 256) {
            int idx = b * 256 + t;
            int n = idx & 511, k = idx >> 9;
            float v = isf ? ((const float*)W1)[k * 512 + n]
                          : bf2f(((const ushort_t*)W1)[k * 512 + n]);
            W1t[n * 128 + k] = f2bf(v);
        } else {
            int i = (b - 256) * 256 + t;
            if (i < PTOT) {
                const void* src; int off;
                if (i < 512)       { src = as1; off = i; }
                else if (i < 1024) { src = ad1; off = i - 512; }
                else if (i < 1536) { src = b1;  off = i - 1024; }
                else if (i < 6656) { src = W2;  off = i - 1536; }
                else if (i < 6666) { src = as2; off = i - 6656; }
                else if (i < 6676) { src = ad2; off = i - 6666; }
                else               { src = b2;  off = i - 6676; }
                prm[i] = isf ? ((const float*)src)[off] : bf2f(((const ushort_t*)src)[off]);
            }
        }
    } else if (b < 362) {
        int i = (b - 283) * 256 + t;
        if (i < N) deg[i] = 0;
    } else {
        for (int i = t; i < 768; i += 256) gacc[i] = 0.f;   // 640 sums + 64 counts + donecnt
    }
}

// ------ fused GEMM1 (+logits) and degree histogram; hist also records each
// edge's within-dst slot (epos) so k_scatter needs no atomics ------
__global__ __launch_bounds__(256) void k_gemm_hist(const void* __restrict__ xraw,
                                                   const ushort_t* __restrict__ w1t,
                                                   const float* __restrict__ prm,
                                                   const int* __restrict__ ei,
                                                   const int* __restrict__ flag,
                                                   uchar_t* __restrict__ h1,
                                                   float* __restrict__ asrcf,
                                                   float* __restrict__ adstf,
                                                   int* __restrict__ deg,
                                                   int* __restrict__ epos,
                                                   int E, int Etot) {
    int b = blockIdx.x, t = threadIdx.x;
    if (b >= 1250) {
        int e = (b - 1250) * 256 + t;
        if (e < Etot) {
            int dst = (e < E) ? ei[E + e] : (e - E);
            epos[e] = atomicAdd(&deg[dst], 1);
        }
        return;
    }
    int wave = t >> 6, lane = t & 63;
    int m0 = b * 16;
    bool isf = (*flag != 0);
    __shared__ ushort_t sA[16 * 128];
    {
        ushort_t tmp[8];
        if (isf) {
            const float4* x4 = (const float4*)((const float*)xraw + (size_t)m0 * 128);
            float4 f0 = x4[2 * t], f1 = x4[2 * t + 1];
            tmp[0] = f2bf(f0.x); tmp[1] = f2bf(f0.y); tmp[2] = f2bf(f0.z); tmp[3] = f2bf(f0.w);
            tmp[4] = f2bf(f1.x); tmp[5] = f2bf(f1.y); tmp[6] = f2bf(f1.z); tmp[7] = f2bf(f1.w);
        } else {
            const uint4* x4 = (const uint4*)((const ushort_t*)xraw + (size_t)m0 * 128);
            uint4 u = x4[t];
            __builtin_memcpy(tmp, &u, 16);
        }
        *reinterpret_cast<uint4*>(&sA[t * 8]) = *reinterpret_cast<uint4*>(tmp);
    }
    __syncthreads();
    int mr = lane & 15, quad = lane >> 4;
    int n0 = wave * 128;
    f32x4 acc[8];
#pragma unroll
    for (int ct = 0; ct < 8; ++ct) acc[ct] = {0.f, 0.f, 0.f, 0.f};
#pragma unroll
    for (int kk = 0; kk < 4; ++kk) {
        bf16x8 a = *reinterpret_cast<const bf16x8*>(&sA[mr * 128 + quad * 8 + kk * 32]);
#pragma unroll
        for (int ct = 0; ct < 8; ++ct) {
            bf16x8 bb = *reinterpret_cast<const bf16x8*>(
                &w1t[(size_t)(n0 + ct * 16 + mr) * 128 + quad * 8 + kk * 32]);
            acc[ct] = __builtin_amdgcn_mfma_f32_16x16x32_bf16(a, bb, acc[ct], 0, 0, 0);
        }
    }
    int col = lane & 15;
#pragma unroll
    for (int hh = 0; hh < 2; ++hh) {
        float ps[4] = {0.f, 0.f, 0.f, 0.f}, pd[4] = {0.f, 0.f, 0.f, 0.f};
#pragma unroll
        for (int c4 = 0; c4 < 4; ++c4) {
            int ct = hh * 4 + c4;
            int abscol = n0 + ct * 16 + col;
            float asv = prm[PO_AS1 + abscol];
            float adv = prm[PO_AD1 + abscol];
#pragma unroll
            for (int r = 0; r < 4; ++r) {
                h1[(size_t)(m0 + quad * 4 + r) * 512 + abscol] = f2fp8(acc[ct][r]);
                ps[r] += acc[ct][r] * asv;
                pd[r] += acc[ct][r] * adv;
            }
        }
#pragma unroll
        for (int off = 1; off <= 8; off <<= 1) {
#pragma unroll
            for (int r = 0; r < 4; ++r) {
                ps[r] += __shfl_xor(ps[r], off, 64);
                pd[r] += __shfl_xor(pd[r], off, 64);
            }
        }
        if (col == 0) {
            int head = 2 * wave + hh;
#pragma unroll
            for (int r = 0; r < 4; ++r) {
                asrcf[(m0 + quad * 4 + r) * 8 + head] = ps[r];
                adstf[(m0 + quad * 4 + r) * 8 + head] = pd[r];
            }
        }
    }
}

// ---- exclusive scan (rowptr only; cursor no longer needed) ----
__global__ __launch_bounds__(256) void k_scan(const int* __restrict__ deg,
                                              int* __restrict__ rowptr, int N) {
    int b = blockIdx.x, t = threadIdx.x;
    int lane = t & 63, wv = t >> 6;
    __shared__ int ws[4], wt[4];
    __shared__ int sbase;
    int limit = b * 256;
    int p0 = 0, p1 = 0, p2 = 0, p3 = 0;
    int i = t;
    for (; i + 768 < limit; i += 1024) {
        p0 += deg[i]; p1 += deg[i + 256]; p2 += deg[i + 512]; p3 += deg[i + 768];
    }
    for (; i < limit; i += 256) p0 += deg[i];
    int partial = (p0 + p1) + (p2 + p3);
#pragma unroll
    for (int off = 32; off; off >>= 1) partial += __shfl_xor(partial, off, 64);
    if (lane == 0) ws[wv] = partial;
    __syncthreads();
    if (t == 0) sbase = ws[0] + ws[1] + ws[2] + ws[3];
    __syncthreads();
    int base = sbase;
    i = limit + t;
    int v = (i < N) ? deg[i] : 0;
    int inc = v;
#pragma unroll
    for (int off = 1; off < 64; off <<= 1) {
        int u = __shfl_up(inc, off, 64);
        if (lane >= off) inc += u;
    }
    if (lane == 63) wt[wv] = inc;
    __syncthreads();
    int woff = 0;
    for (int w = 0; w < 4; ++w) if (w < wv) woff += wt[w];
    int excl = base + woff + inc - v;
    if (i < N) rowptr[i + 1] = excl + v;
    if (i == 0) rowptr[0] = 0;
}

// ---- atomic-free scatter: slot precomputed in hist (epos) ----
__global__ __launch_bounds__(256) void k_scatter(const int* __restrict__ ei,
                                                 const int* __restrict__ rowptr,
                                                 const int* __restrict__ epos,
                                                 int* __restrict__ csr_src,
                                                 int E, int Etot) {
    int e = blockIdx.x * 256 + threadIdx.x;
    if (e >= Etot) return;
    int src, dst;
    if (e < E) { src = ei[e]; dst = ei[E + e]; } else { src = dst = e - E; }
    csr_src[rowptr[dst] + epos[e]] = src;
}

// --- layer-1 agg + ELU + layer-2 linear&logits. R0/R9-verified structure:
// ONE wave per node (4/block), 8-edge batches, in-loop asrcf gather +
// leaky + exp. Split into two dispatches via nbase (diagnostic: exposes
// background kernels in rocprof top-5; math identical). ---
__global__ __launch_bounds__(256) void k_agg1(const uchar_t* __restrict__ h1,
                                              const float* __restrict__ asrcf,
                                              const float* __restrict__ adstf,
                                              const int* __restrict__ rowptr,
                                              const int* __restrict__ csr_src,
                                              const float* __restrict__ prm,
                                              ushort_t* __restrict__ h2,
                                              float* __restrict__ asrc2f,
                                              float* __restrict__ adst2f,
                                              int nbase) {
    int n = nbase + blockIdx.x * 4 + (threadIdx.x >> 6);
    int lane = threadIdx.x & 63;
    int hh = lane >> 3;
    int cb = lane * 8;
    int start = rowptr[n], end = rowptr[n + 1];
    int deg = end - start;
    float adh = adstf[n * 8 + hh];
    float a0 = 0.f, a1 = 0.f, a2 = 0.f, a3 = 0.f, a4 = 0.f, a5 = 0.f, a6 = 0.f, a7 = 0.f;
    float den = 0.f;
    for (int base = 0; base < deg; base += 64) {
        int m = min(64, deg - base);
        int sIdx = csr_src[start + base + min(lane, m - 1)];
        for (int g = 0; g < m; g += 8) {
            int s[8]; float lo[8]; uint2 p[8];
#pragma unroll
            for (int j = 0; j < 8; ++j)
                s[j] = __shfl(sIdx, min(g + j, m - 1), 64);
#pragma unroll
            for (int j = 0; j < 8; ++j)
                lo[j] = asrcf[s[j] * 8 + hh];
#pragma unroll
            for (int j = 0; j < 8; ++j)
                p[j] = *reinterpret_cast<const uint2*>(&h1[(size_t)s[j] * 512 + cb]);
#pragma unroll
            for (int j = 0; j < 8; ++j) {
                float we = (g + j < m) ? __expf(leaky(lo[j] + adh)) : 0.f;
                den += we;
                f32x2 q0 = __builtin_amdgcn_cvt_pk_f32_fp8((int)p[j].x, false);
                f32x2 q1 = __builtin_amdgcn_cvt_pk_f32_fp8((int)p[j].x, true);
                f32x2 q2 = __builtin_amdgcn_cvt_pk_f32_fp8((int)p[j].y, false);
                f32x2 q3 = __builtin_amdgcn_cvt_pk_f32_fp8((int)p[j].y, true);
                a0 += we * q0.x; a1 += we * q0.y;
                a2 += we * q1.x; a3 += we * q1.y;
                a4 += we * q2.x; a5 += we * q2.y;
                a6 += we * q3.x; a7 += we * q3.y;
            }
        }
    }
    float inv = 1.f / (den + 1e-16f);
    float r[8] = {a0, a1, a2, a3, a4, a5, a6, a7};
    float p2[10];
#pragma unroll
    for (int c = 0; c < 10; ++c) p2[c] = 0.f;
#pragma unroll
    for (int j = 0; j < 8; ++j) {
        float rv = r[j] * inv + prm[PO_B1 + cb + j];
        rv = (rv > 0.f) ? rv : expm1f(rv);    // ELU
        const float2* wrow = reinterpret_cast<const float2*>(&prm[PO_W2 + (cb + j) * 10]);
        float2 w01 = wrow[0], w23 = wrow[1], w45 = wrow[2], w67 = wrow[3], w89 = wrow[4];
        p2[0] += rv * w01.x; p2[1] += rv * w01.y;
        p2[2] += rv * w23.x; p2[3] += rv * w23.y;
        p2[4] += rv * w45.x; p2[5] += rv * w45.y;
        p2[6] += rv * w67.x; p2[7] += rv * w67.y;
        p2[8] += rv * w89.x; p2[9] += rv * w89.y;
    }
#pragma unroll
    for (int c = 0; c < 10; ++c)
#pragma unroll
        for (int off = 32; off; off >>= 1)
            p2[c] += __shfl_xor(p2[c], off, 64);
    if (lane == 0) {
        float as = 0.f, ad = 0.f;
#pragma unroll
        for (int c = 0; c < 10; ++c) {
            h2[(size_t)n * 16 + c] = f2bf(p2[c]);   // bf16 32B rows
            as += p2[c] * prm[PO_AS2 + c];
            ad += p2[c] * prm[PO_AD2 + c];
        }
        asrc2f[n] = as; adst2f[n] = ad;
    }
}

// ------- layer-2 softmax+agg, 16 lanes/node, fused mean-pool + counts + final -------
__global__ __launch_bounds__(256) void k_agg2f(const ushort_t* __restrict__ h2,
                                               const float* __restrict__ asrc2f,
                                               const float* __restrict__ adst2f,
                                               const int* __restrict__ rowptr,
                                               const int* __restrict__ csr_src,
                                               const float* __restrict__ prm,
                                               const int* __restrict__ batch,
                                               float* __restrict__ gacc,
                                               float* __restrict__ gcnt,
                                               int* __restrict__ donecnt,
                                               const int* __restrict__ flag,
                                               void* __restrict__ dout) {
    int t = threadIdx.x;
    int grp = t >> 4, l = t & 15;
    int n = blockIdx.x * 16 + grp;
    int start = rowptr[n], end = rowptr[n + 1];
    float adn = adst2f[n];
    float den = 0.f;
    float oc[10];
#pragma unroll
    for (int c = 0; c < 10; ++c) oc[c] = 0.f;
    for (int e = start + l; e < end; e += 16) {
        int s = csr_src[e];
        float lo = asrc2f[s];
        const uint_t* hp = (const uint_t*)(h2 + (size_t)s * 16);
        uint4 ha = *(const uint4*)hp;
        uint_t hb = hp[4];
        float ee = __expf(leaky(lo + adn));
        den += ee;
        oc[0] += ee * bf2f(ha.x & 0xffff); oc[1] += ee * bf2f(ha.x >> 16);
        oc[2] += ee * bf2f(ha.y & 0xffff); oc[3] += ee * bf2f(ha.y >> 16);
        oc[4] += ee * bf2f(ha.z & 0xffff); oc[5] += ee * bf2f(ha.z >> 16);
        oc[6] += ee * bf2f(ha.w & 0xffff); oc[7] += ee * bf2f(ha.w >> 16);
        oc[8] += ee * bf2f(hb & 0xffff);   oc[9] += ee * bf2f(hb >> 16);
    }
#pragma unroll
    for (int off = 8; off; off >>= 1) {
        den += __shfl_xor(den, off, 64);
#pragma unroll
        for (int c = 0; c < 10; ++c) oc[c] += __shfl_xor(oc[c], off, 64);
    }
    __shared__ float sres[16][12];
    __shared__ int sg[16];
    if (l == 0) {
        float invd = 1.f / (den + 1e-16f);
#pragma unroll
        for (int c = 0; c < 10; ++c) sres[grp][c] = oc[c] * invd + prm[PO_B2 + c];
        sres[grp][10] = 1.f;
        sg[grp] = batch[n];
    }
    __syncthreads();
    if (t < 11) {
        int c = t;
        float run = sres[0][c]; int g = sg[0];
        for (int k = 1; k < 16; ++k) {
            if (sg[k] != g) {
                atomicAdd(c < 10 ? &gacc[g * 10 + c] : &gcnt[g], run);
                g = sg[k]; run = 0.f;
            }
            run += sres[k][c];
        }
        atomicAdd(c < 10 ? &gacc[g * 10 + c] : &gcnt[g], run);
    }
    // ---- last block performs the final divide + store ----
    __syncthreads();
    __shared__ int slast;
    if (t == 0) {
        __threadfence();
        int d = atomicAdd(donecnt, 1);
        slast = (d == (int)gridDim.x - 1) ? 1 : 0;
    }
    __syncthreads();
    if (slast && t < 64) {
        __threadfence();
        bool isf = (*flag != 0);
        const volatile float* ga = (const volatile float*)gacc;
        const volatile float* gc = (const volatile float*)gcnt;
        float cnt = fmaxf(gc[t], 1.f);
        for (int c = 0; c < 10; ++c) {
            float r = ga[t * 10 + c] / cnt;
            if (isf) ((float*)dout)[t * 10 + c] = r;
            else     ((ushort_t*)dout)[t * 10 + c] = f2bf(r);
        }
    }
}

extern "C" void kernel_launch(void* const* d_in, const int* in_sizes, int n_in,
                              void* d_out, int out_size, void* d_ws, size_t ws_size,
                              hipStream_t stream) {
    const void* x   = d_in[0];
    const int* ei   = (const int*)d_in[1];
    const int* batch= (const int*)d_in[2];
    const void* W1  = d_in[3];
    const void* as1 = d_in[4];
    const void* ad1 = d_in[5];
    const void* b1  = d_in[6];
    const void* W2  = d_in[7];
    const void* as2 = d_in[8];
    const void* ad2 = d_in[9];
    const void* b2  = d_in[10];

    constexpr int N = 20000, E = 320000, Etot = E + N;
    constexpr int histBlocks = (Etot + 255) / 256;

    char* p = (char*)d_ws;
    auto alloc = [&](size_t bytes) {
        char* r = p; p += (bytes + 255) & ~(size_t)255; return r;
    };
    int* flag       = (int*)alloc(256);
    float* prm      = (float*)alloc((size_t)PTOT * 4);
    ushort_t* w1t   = (ushort_t*)alloc(512 * 128 * 2);
    uchar_t* h1     = (uchar_t*)alloc((size_t)N * 512);           // 10.24 MB fp8
    float* asrc1f   = (float*)alloc((size_t)N * 8 * 4);
    float* adst1f   = (float*)alloc((size_t)N * 8 * 4);
    float* asrc2f   = (float*)alloc((size_t)N * 4);
    float* adst2f   = (float*)alloc((size_t)N * 4);
    ushort_t* h2    = (ushort_t*)alloc((size_t)N * 16 * 2);       // bf16 32B rows
    float* gacc     = (float*)alloc((size_t)768 * 4);             // sums+counts+done
    int* deg        = (int*)alloc((size_t)N * 4);
    int* rowptr     = (int*)alloc((size_t)(N + 1) * 4);
    int* epos       = (int*)alloc((size_t)Etot * 4);
    int* csr_src    = (int*)alloc((size_t)(Etot + 64) * 4);
    float* gcnt     = gacc + 640;
    int* donecnt    = (int*)(gacc + 704);

    k_prep<<<363, 256, 0, stream>>>(x, W1, as1, ad1, b1, W2, as2, ad2, b2,
                                    w1t, prm, deg, gacc, flag, N);
    k_gemm_hist<<<1250 + histBlocks, 256, 0, stream>>>(x, w1t, prm, ei, flag, h1,
                                                       asrc1f, adst1f, deg, epos, E, Etot);
    k_scan<<<(N + 255) / 256, 256, 0, stream>>>(deg, rowptr, N);
    k_scatter<<<histBlocks, 256, 0, stream>>>(ei, rowptr, epos, csr_src, E, Etot);
    k_agg1<<<N / 8, 256, 0, stream>>>(h1, asrc1f, adst1f, rowptr, csr_src, prm,
                                      h2, asrc2f, adst2f, 0);
    k_agg1<<<N / 8, 256, 0, stream>>>(h1, asrc1f, adst1f, rowptr, csr_src, prm,
                                      h2, asrc2f, adst2f, N / 2);
    k_agg2f<<<N / 16, 256, 0, stream>>>(h2, asrc2f, adst2f, rowptr, csr_src, prm,
                                        batch, gacc, gcnt, donecnt, flag, d_out);
}